// Round 1
// baseline (3665.237 us; speedup 1.0000x reference)
//
#include <hip/hip_runtime.h>
#include <hip/hip_bf16.h>

#define B_    8
#define C_    320
#define H_    160
#define W_    160
#define D_    160
#define HD_   32
#define NH_   5
#define HW_   25600
#define NPIX_ 204800
#define NQ_   960
#define S_    160

// ---------------- kernel 1: fold conv weights into QKV projections --------
// WT[c][o] (o-major, 320x960) : combined weight so  qkv[p][o] = xn[p][.] dot WT[.][o]
// bc[o]: combined bias.
__global__ void build_wcomb_k(
    const float* __restrict__ conv_w, const float* __restrict__ conv_b,
    const float* __restrict__ w0, const float* __restrict__ b0,
    const float* __restrict__ w1, const float* __restrict__ b1,
    const float* __restrict__ w2, const float* __restrict__ b2,
    const float* __restrict__ w3, const float* __restrict__ b3,
    const float* __restrict__ w4, const float* __restrict__ b4,
    const float* __restrict__ w5, const float* __restrict__ b5,
    float* __restrict__ WT, float* __restrict__ bc)
{
    int idx = blockIdx.x * blockDim.x + threadIdx.x;
    if (idx >= C_ * NQ_) return;
    int c = idx / NQ_;
    int o = idx % NQ_;
    int j = o / D_;     // 0..5 : qh,kh,vh,qv,kv,vv
    int d = o % D_;
    const float* wj; const float* bj;
    switch (j) {
        case 0: wj = w0; bj = b0; break;
        case 1: wj = w1; bj = b1; break;
        case 2: wj = w2; bj = b2; break;
        case 3: wj = w3; bj = b3; break;
        case 4: wj = w4; bj = b4; break;
        default: wj = w5; bj = b5; break;
    }
    int off = (j < 3) ? 0 : D_;
    float acc = 0.f;
    for (int e = 0; e < D_; ++e)
        acc += wj[d * D_ + e] * conv_w[(size_t)(off + e) * C_ + c];
    WT[(size_t)c * NQ_ + o] = acc;
    if (c == 0) {
        float bacc = bj[d];
        for (int e = 0; e < D_; ++e)
            bacc += wj[d * D_ + e] * conv_b[off + e];
        bc[o] = bacc;
    }
}

// ---------------- kernel 2: per-pixel LayerNorm stats ---------------------
// x is (B,C,H,W). pixel p = (b*H+h)*W + w ; addr(p,c) = p + c*HW + b*(C-1)*HW
__global__ void ln_stats_k(const float* __restrict__ x,
                           float* __restrict__ mu, float* __restrict__ rstd)
{
    int p = blockIdx.x * blockDim.x + threadIdx.x;
    if (p >= NPIX_) return;
    int b = p / HW_;
    const float* xp = x + (size_t)p + (size_t)b * (C_ - 1) * HW_;
    float s = 0.f, s2 = 0.f;
    for (int c = 0; c < C_; ++c) {
        float v = xp[(size_t)c * HW_];
        s += v; s2 += v * v;
    }
    float m = s * (1.f / C_);
    float var = s2 * (1.f / C_) - m * m;
    mu[p] = m;
    rstd[p] = rsqrtf(var + 1e-5f);
}

// ---------------- kernel 3: fused LN + combined GEMM ----------------------
// A = xn (204800 x 320) built on the fly, B = WT (320 x 960), out bf16 QKV.
__global__ __launch_bounds__(256) void gemm_qkv_k(
    const float* __restrict__ x, const float* __restrict__ mu,
    const float* __restrict__ rstd,
    const float* __restrict__ ln_g, const float* __restrict__ ln_b,
    const float* __restrict__ WT, const float* __restrict__ bc,
    __hip_bfloat16* __restrict__ qkv)
{
    __shared__ float As[16][64];
    __shared__ float Bs[16][64];

    const int tid = threadIdx.x;
    const int m0 = blockIdx.y * 64;
    const int n0 = blockIdx.x * 64;
    const int bb = m0 / HW_;                       // 64 | 25600, no crossing
    const size_t abase = (size_t)m0 + (size_t)bb * (C_ - 1) * HW_;

    const int tx = tid & 15;    // n
    const int ty = tid >> 4;    // m

    float acc[4][4];
#pragma unroll
    for (int i = 0; i < 4; ++i)
#pragma unroll
        for (int j = 0; j < 4; ++j) acc[i][j] = 0.f;

    for (int k0 = 0; k0 < C_; k0 += 16) {
#pragma unroll
        for (int r = 0; r < 4; ++r) {
            int q  = tid + 256 * r;       // 0..1023
            int m  = q & 63;
            int kk = q >> 6;
            int c  = k0 + kk;
            int p  = m0 + m;
            float v = x[abase + m + (size_t)c * HW_];
            As[kk][m] = (v - mu[p]) * rstd[p] * ln_g[c] + ln_b[c];
            Bs[kk][m] = WT[(size_t)c * NQ_ + n0 + m];
        }
        __syncthreads();
#pragma unroll
        for (int kk = 0; kk < 16; ++kk) {
            float af[4], bf[4];
#pragma unroll
            for (int i = 0; i < 4; ++i) af[i] = As[kk][ty * 4 + i];
#pragma unroll
            for (int j = 0; j < 4; ++j) bf[j] = Bs[kk][tx * 4 + j];
#pragma unroll
            for (int i = 0; i < 4; ++i)
#pragma unroll
                for (int j = 0; j < 4; ++j)
                    acc[i][j] += af[i] * bf[j];
        }
        __syncthreads();
    }

#pragma unroll
    for (int i = 0; i < 4; ++i) {
        int p = m0 + ty * 4 + i;
#pragma unroll
        for (int j = 0; j < 4; ++j) {
            int n = n0 + tx * 4 + j;
            qkv[(size_t)p * NQ_ + n] = __float2bfloat16(acc[i][j] + bc[n]);
        }
    }
}

// ---------------- kernel 4: attention ------------------------------------
// grid: 2 branches * 1280 seqs * 5 heads. block = 192 threads.
// QKV columns: [0,160)=qh [160,320)=kh [320,480)=vh [480,640)=qv [640,800)=kv [800,960)=vv
__global__ __launch_bounds__(192) void attn_k(
    const __hip_bfloat16* __restrict__ qkv, float* __restrict__ out)
{
    __shared__ float Ks[S_][HD_];
    __shared__ float Vs[S_][HD_];

    int blk    = blockIdx.x;
    int branch = blk / (1280 * NH_);
    int rem    = blk % (1280 * NH_);
    int s      = rem / NH_;
    int head   = rem % NH_;

    int qofs = branch ? 480 : 0;
    int kofs = qofs + 160;
    int vofs = qofs + 320;
    int col  = head * HD_;

    int pbase, pstride;
    if (branch == 0) { pbase = s * W_; pstride = 1; }
    else { int b = s / W_, w = s % W_; pbase = b * HW_ + w; pstride = W_; }

    for (int i = threadIdx.x; i < S_ * HD_; i += blockDim.x) {
        int j = i / HD_, e = i % HD_;
        size_t row = (size_t)(pbase + j * pstride) * NQ_;
        Ks[j][e] = __bfloat162float(qkv[row + kofs + col + e]);
        Vs[j][e] = __bfloat162float(qkv[row + vofs + col + e]);
    }
    __syncthreads();

    int t = threadIdx.x;
    if (t < S_) {
        float q[HD_];
        size_t qrow = (size_t)(pbase + t * pstride) * NQ_ + qofs + col;
#pragma unroll
        for (int e = 0; e < HD_; ++e) q[e] = __bfloat162float(qkv[qrow + e]);

        const float scale = 0.17677669529663689f;   // 1/sqrt(32)

        float mx = -1e30f;
        for (int j = 0; j < S_; ++j) {
            float d = 0.f;
#pragma unroll
            for (int e = 0; e < HD_; ++e) d += q[e] * Ks[j][e];
            mx = fmaxf(mx, d * scale);
        }

        float l = 0.f;
        float acc[HD_];
#pragma unroll
        for (int e = 0; e < HD_; ++e) acc[e] = 0.f;

        for (int j = 0; j < S_; ++j) {
            float d = 0.f;
#pragma unroll
            for (int e = 0; e < HD_; ++e) d += q[e] * Ks[j][e];
            float p = __expf(d * scale - mx);
            l += p;
#pragma unroll
            for (int e = 0; e < HD_; ++e) acc[e] += p * Vs[j][e];
        }
        float inv = 1.f / l;

        if (branch == 0) {
            int b = s / H_, h = s % H_;
            size_t base = (((size_t)b * D_) * H_ + h) * W_ + t;
#pragma unroll
            for (int e = 0; e < HD_; ++e)
                out[base + (size_t)(col + e) * HW_] = acc[e] * inv;
        } else {
            int b = s / W_, w = s % W_;
            size_t base = ((size_t)(B_ + b) * D_) * HW_ + (size_t)t * W_ + w;
#pragma unroll
            for (int e = 0; e < HD_; ++e)
                out[base + (size_t)(col + e) * HW_] = acc[e] * inv;
        }
    }
}

// ---------------- launcher ------------------------------------------------
extern "C" void kernel_launch(void* const* d_in, const int* in_sizes, int n_in,
                              void* d_out, int out_size, void* d_ws, size_t ws_size,
                              hipStream_t stream)
{
    const float* x      = (const float*)d_in[0];
    const float* ln_g   = (const float*)d_in[1];
    const float* ln_b   = (const float*)d_in[2];
    const float* conv_w = (const float*)d_in[3];
    const float* conv_b = (const float*)d_in[4];
    const float* wqh = (const float*)d_in[5];  const float* bqh = (const float*)d_in[6];
    const float* wkh = (const float*)d_in[7];  const float* bkh = (const float*)d_in[8];
    const float* wvh = (const float*)d_in[9];  const float* bvh = (const float*)d_in[10];
    const float* wqv = (const float*)d_in[11]; const float* bqv = (const float*)d_in[12];
    const float* wkv = (const float*)d_in[13]; const float* bkv = (const float*)d_in[14];
    const float* wvv = (const float*)d_in[15]; const float* bvv = (const float*)d_in[16];

    float* out = (float*)d_out;

    // workspace layout
    char* ws = (char*)d_ws;
    size_t off = 0;
    __hip_bfloat16* qkv = (__hip_bfloat16*)(ws + off); off += (size_t)NPIX_ * NQ_ * 2;  // 393,216,000
    float* WT   = (float*)(ws + off); off += (size_t)C_ * NQ_ * 4;                      // 1,228,800
    float* bc   = (float*)(ws + off); off += NQ_ * 4;
    float* mu   = (float*)(ws + off); off += (size_t)NPIX_ * 4;
    float* rstd = (float*)(ws + off); off += (size_t)NPIX_ * 4;

    // 1. combined weights
    {
        int n = C_ * NQ_;
        build_wcomb_k<<<(n + 255) / 256, 256, 0, stream>>>(
            conv_w, conv_b, wqh, bqh, wkh, bkh, wvh, bvh,
            wqv, bqv, wkv, bkv, wvv, bvv, WT, bc);
    }
    // 2. LN stats
    ln_stats_k<<<NPIX_ / 256, 256, 0, stream>>>(x, mu, rstd);

    // 3. fused LN + GEMM -> QKV (bf16)
    {
        dim3 grid(NQ_ / 64, NPIX_ / 64);
        gemm_qkv_k<<<grid, 256, 0, stream>>>(x, mu, rstd, ln_g, ln_b, WT, bc, qkv);
    }
    // 4. attention (both branches)
    attn_k<<<2 * 1280 * NH_, 192, 0, stream>>>(qkv, out);
}